// Round 4
// baseline (421.815 us; speedup 1.0000x reference)
//
#include <hip/hip_runtime.h>
#include <hip/hip_bf16.h>

// Problem constants
#define N_ROWS 8192
#define D_DIM  1024
#define HALF_N 4096
constexpr float INV_T = 1.0f / 0.07f;   // 14.2857143 — also the fixed softmax max M

typedef __attribute__((ext_vector_type(8))) short short8;  // 8 bf16 (4 VGPRs)
typedef __attribute__((ext_vector_type(4))) float f32x4;

__device__ __forceinline__ unsigned short f2bf(float x) {
    __hip_bfloat16 h = __float2bfloat16(x);
    return *reinterpret_cast<unsigned short*>(&h);
}

__device__ __forceinline__ float bf2f(unsigned short u) {
    unsigned int v = ((unsigned int)u) << 16;
    return __int_as_float((int)v);
}

// async global->LDS, 16B/lane. LDS dest is wave-uniform base + lane*16.
__device__ __forceinline__ void async_ld16(const void* g, void* lds) {
    __builtin_amdgcn_global_load_lds(
        (const __attribute__((address_space(1))) void*)g,
        (__attribute__((address_space(3))) void*)lds,
        16, 0, 0);
}

// ---------------------------------------------------------------------------
// Kernel 1: row norms + bf16 normalized copy + row_sum zeroing.
// One wave per row.
__global__ __launch_bounds__(256) void norm_kernel(const float* __restrict__ feat,
                                                   unsigned short* __restrict__ fn,
                                                   float* __restrict__ row_sum) {
    const int w = threadIdx.x >> 6, lane = threadIdx.x & 63;
    const int row = blockIdx.x * 4 + w;
    const float4* src = (const float4*)(feat + (size_t)row * D_DIM);
    float4 v[4];
    float ss = 0.f;
#pragma unroll
    for (int t = 0; t < 4; ++t) {
        v[t] = src[lane + 64 * t];
        ss += v[t].x * v[t].x + v[t].y * v[t].y + v[t].z * v[t].z + v[t].w * v[t].w;
    }
#pragma unroll
    for (int off = 32; off; off >>= 1) ss += __shfl_xor(ss, off);
    float nrm = fmaxf(sqrtf(ss), 1e-8f);
    if (lane == 0) row_sum[row] = 0.f;
    const float inv = 1.0f / nrm;
    ushort4* dst = (ushort4*)(fn + (size_t)row * D_DIM);
#pragma unroll
    for (int t = 0; t < 4; ++t) {
        ushort4 o;
        o.x = f2bf(v[t].x * inv);
        o.y = f2bf(v[t].y * inv);
        o.z = f2bf(v[t].z * inv);
        o.w = f2bf(v[t].w * inv);
        dst[lane + 64 * t] = o;
    }
}

// ---------------------------------------------------------------------------
// Kernel 2: s_target[i] = dot(fn_i, fn_pair) / T from the bf16 normalized
// rows (same quantization as the GEMM path). One wave per row.
__global__ __launch_bounds__(256) void target_kernel(const unsigned short* __restrict__ fn,
                                                     float* __restrict__ s_target) {
    const int w = threadIdx.x >> 6, lane = threadIdx.x & 63;
    const int row = blockIdx.x * 4 + w;
    const int pair = (row + HALF_N) & (N_ROWS - 1);
    const short8* a = (const short8*)(fn + (size_t)row * D_DIM);
    const short8* b = (const short8*)(fn + (size_t)pair * D_DIM);
    float d = 0.f;
#pragma unroll
    for (int t = 0; t < 2; ++t) {
        short8 x = a[lane + 64 * t], y = b[lane + 64 * t];
#pragma unroll
        for (int e = 0; e < 8; ++e)
            d += bf2f((unsigned short)x[e]) * bf2f((unsigned short)y[e]);
    }
#pragma unroll
    for (int off = 32; off; off >>= 1) d += __shfl_xor(d, off);
    if (lane == 0) s_target[row] = d * INV_T;
}

// ---------------------------------------------------------------------------
// Kernel 3: flash-style sim GEMM (NT, A=B=fn) + fixed-max exp accumulation.
// Round-1 structure (BK=32, 16 KiB LDS) with UNIT-MAJOR staging permutation:
// chunk = 16 rows x 32 k (1 KiB); staging lane l fetches (row=l&15,
// unit=l>>4) so physical offset of (row,unit) = (unit*16+row)*16B. Fragment
// read addr = chunk_base + (q*16+c16)*16B -> quarter-wave bank-starts
// c16*4 mod 32 sweep all 32 banks: conflict-free b128, and the address is a
// single kt-invariant register + constant ds offsets (round-1 reg profile —
// the XOR-swizzle of rounds 2/3 cost +88 VGPR and 1 wave/SIMD; this costs 0).
// K-loop global pointers are strength-reduced (+32 elts/kt).
__global__ __launch_bounds__(256, 3) void simgemm_kernel(const unsigned short* __restrict__ fn,
                                                         float* __restrict__ row_sum) {
    __shared__ __align__(16) unsigned short As[128 * 32];   // 8 KiB
    __shared__ __align__(16) unsigned short Bs[128 * 32];   // 8 KiB
    const int tid = threadIdx.x;
    const int w = tid >> 6, lane = tid & 63;
    const int q = lane >> 4, c16 = lane & 15;
    const int r0 = blockIdx.y * 128;
    const int cg0 = blockIdx.x * 512;
    const int wr = (w >> 1) * 64;  // wave's row base within tile
    const int wc = (w & 1) * 64;   // wave's col base within tile
    const int wr4 = (w >> 1) * 4;  // wave's A chunk base (16-row chunks)
    const int wc4 = (w & 1) * 4;   // wave's B chunk base
    // staging: wave w stages chunks 2w, 2w+1 of A and B.
    const int srow = lane & 15;          // row within chunk
    const int sue = (lane >> 4) * 8;     // unit element offset
    const int loff = (q * 16 + c16) * 8; // LDS fragment element offset in chunk

    const unsigned short* pa0 = fn + (size_t)(r0 + w * 32 + srow) * D_DIM + sue;
    const unsigned short* pa1 = pa0 + 16 * D_DIM;

    float rs[4][4];                      // per-(row-subtile, reg) partial exp-sums
#pragma unroll
    for (int i = 0; i < 4; ++i)
#pragma unroll
        for (int r = 0; r < 4; ++r) rs[i][r] = 0.f;

    for (int ct = 0; ct < 4; ++ct) {
        const int c0 = cg0 + ct * 128;
        const unsigned short* qa0 = pa0;
        const unsigned short* qa1 = pa1;
        const unsigned short* pb0 = fn + (size_t)(c0 + w * 32 + srow) * D_DIM + sue;
        const unsigned short* pb1 = pb0 + 16 * D_DIM;

        f32x4 acc[4][4];
#pragma unroll
        for (int i = 0; i < 4; ++i)
#pragma unroll
            for (int j = 0; j < 4; ++j) acc[i][j] = (f32x4){0.f, 0.f, 0.f, 0.f};

        for (int kt = 0; kt < 32; ++kt) {
            __syncthreads();  // previous k-step's reads done before overwrite
            async_ld16(qa0, (void*)&As[(w * 2 + 0) * 512]);
            async_ld16(qa1, (void*)&As[(w * 2 + 1) * 512]);
            async_ld16(pb0, (void*)&Bs[(w * 2 + 0) * 512]);
            async_ld16(pb1, (void*)&Bs[(w * 2 + 1) * 512]);
            qa0 += 32; qa1 += 32; pb0 += 32; pb1 += 32;
            __syncthreads();  // drains vmcnt(0): staging visible

            short8 af[4], bf[4];
#pragma unroll
            for (int i = 0; i < 4; ++i)
                af[i] = *(const short8*)&As[(wr4 + i) * 512 + loff];
#pragma unroll
            for (int j = 0; j < 4; ++j)
                bf[j] = *(const short8*)&Bs[(wc4 + j) * 512 + loff];
#pragma unroll
            for (int i = 0; i < 4; ++i)
#pragma unroll
                for (int j = 0; j < 4; ++j)
                    acc[i][j] = __builtin_amdgcn_mfma_f32_16x16x32_bf16(af[i], bf[j], acc[i][j], 0, 0, 0);
        }

        // epilogue: exp(sim - M), diag masked, accumulate per-row
#pragma unroll
        for (int i = 0; i < 4; ++i) {
            const int growb = r0 + wr + i * 16 + q * 4;
#pragma unroll
            for (int r = 0; r < 4; ++r) {
                float s = 0.f;
#pragma unroll
                for (int j = 0; j < 4; ++j) {
                    const int gcol = c0 + wc + j * 16 + c16;
                    float sim = acc[i][j][r] * INV_T;
                    float e = __expf(sim - INV_T);
                    if (growb + r == gcol) e = 0.f;  // diagonal mask
                    s += e;
                }
                rs[i][r] += s;
            }
        }
    }

    // reduce across the 16 col-lanes of each quad, one atomic per row
#pragma unroll
    for (int i = 0; i < 4; ++i)
#pragma unroll
        for (int r = 0; r < 4; ++r) {
            float s = rs[i][r];
            s += __shfl_xor(s, 1);
            s += __shfl_xor(s, 2);
            s += __shfl_xor(s, 4);
            s += __shfl_xor(s, 8);
            if (c16 == 0) atomicAdd(&row_sum[r0 + wr + i * 16 + q * 4 + r], s);
        }
}

// ---------------------------------------------------------------------------
// Kernel 4: loss = mean_i [ M + log(row_sum_i) - s_target_i ]
__global__ __launch_bounds__(256) void loss_kernel(const float* __restrict__ row_sum,
                                                   const float* __restrict__ s_target,
                                                   float* __restrict__ out) {
    float local = 0.f;
    for (int i = threadIdx.x; i < N_ROWS; i += 256)
        local += (INV_T + __logf(row_sum[i])) - s_target[i];
#pragma unroll
    for (int off = 32; off; off >>= 1) local += __shfl_xor(local, off);
    __shared__ float part[4];
    if ((threadIdx.x & 63) == 0) part[threadIdx.x >> 6] = local;
    __syncthreads();
    if (threadIdx.x == 0)
        out[0] = (part[0] + part[1] + part[2] + part[3]) * (1.0f / N_ROWS);
}

// ---------------------------------------------------------------------------
extern "C" void kernel_launch(void* const* d_in, const int* in_sizes, int n_in,
                              void* d_out, int out_size, void* d_ws, size_t ws_size,
                              hipStream_t stream) {
    const float* feat = (const float*)d_in[0];
    float* out = (float*)d_out;
    char* ws = (char*)d_ws;

    unsigned short* fn = (unsigned short*)ws;                 // 8192*1024 bf16 = 16 MiB
    size_t off = (size_t)N_ROWS * D_DIM * sizeof(unsigned short);
    float* row_sum = (float*)(ws + off);  off += N_ROWS * sizeof(float);
    float* s_target = (float*)(ws + off);

    norm_kernel<<<N_ROWS / 4, 256, 0, stream>>>(feat, fn, row_sum);
    target_kernel<<<N_ROWS / 4, 256, 0, stream>>>(fn, s_target);
    simgemm_kernel<<<dim3(16, 64), 256, 0, stream>>>(fn, row_sum);
    loss_kernel<<<1, 256, 0, stream>>>(row_sum, s_target, out);
}

// Round 5
// 340.254 us; speedup vs baseline: 1.2397x; 1.2397x over previous
//
#include <hip/hip_runtime.h>
#include <hip/hip_bf16.h>

// Problem constants
#define N_ROWS 8192
#define D_DIM  1024
#define HALF_N 4096
constexpr float INV_T = 1.0f / 0.07f;   // 14.2857143 — also the fixed softmax max M

typedef __attribute__((ext_vector_type(8))) short short8;  // 8 bf16 (4 VGPRs)
typedef __attribute__((ext_vector_type(4))) float f32x4;

__device__ __forceinline__ unsigned short f2bf(float x) {
    __hip_bfloat16 h = __float2bfloat16(x);
    return *reinterpret_cast<unsigned short*>(&h);
}

// async global->LDS, 16B/lane. LDS dest is wave-uniform base + lane*16.
__device__ __forceinline__ void async_ld16(const void* g, void* lds) {
    __builtin_amdgcn_global_load_lds(
        (const __attribute__((address_space(1))) void*)g,
        (__attribute__((address_space(3))) void*)lds,
        16, 0, 0);
}

// ---------------------------------------------------------------------------
// Kernel 1: row norms + bf16 normalized copy + fp32-exact target similarity
// + row_sum zeroing. One wave per row; pair row (i+4096 mod 8192) is read
// again here (L3-resident, 16 MB extra) to avoid a separate target kernel.
__global__ __launch_bounds__(256) void norm_kernel(const float* __restrict__ feat,
                                                   unsigned short* __restrict__ fn,
                                                   float* __restrict__ row_sum,
                                                   float* __restrict__ s_target) {
    const int w = threadIdx.x >> 6, lane = threadIdx.x & 63;
    const int row = blockIdx.x * 4 + w;
    const int pair = (row + HALF_N) & (N_ROWS - 1);
    const float4* src = (const float4*)(feat + (size_t)row * D_DIM);
    const float4* psrc = (const float4*)(feat + (size_t)pair * D_DIM);
    float4 v[4];
    float ss = 0.f, sp = 0.f, dp = 0.f;
#pragma unroll
    for (int t = 0; t < 4; ++t) {
        v[t] = src[lane + 64 * t];
        float4 p = psrc[lane + 64 * t];
        ss += v[t].x * v[t].x + v[t].y * v[t].y + v[t].z * v[t].z + v[t].w * v[t].w;
        sp += p.x * p.x + p.y * p.y + p.z * p.z + p.w * p.w;
        dp += v[t].x * p.x + v[t].y * p.y + v[t].z * p.z + v[t].w * p.w;
    }
#pragma unroll
    for (int off = 32; off; off >>= 1) {
        ss += __shfl_xor(ss, off);
        sp += __shfl_xor(sp, off);
        dp += __shfl_xor(dp, off);
    }
    float nrm = fmaxf(sqrtf(ss), 1e-8f);
    if (lane == 0) {
        row_sum[row] = 0.f;
        s_target[row] = dp / (nrm * fmaxf(sqrtf(sp), 1e-8f)) * INV_T;
    }
    const float inv = 1.0f / nrm;
    ushort4* dst = (ushort4*)(fn + (size_t)row * D_DIM);
#pragma unroll
    for (int t = 0; t < 4; ++t) {
        ushort4 o;
        o.x = f2bf(v[t].x * inv);
        o.y = f2bf(v[t].y * inv);
        o.z = f2bf(v[t].z * inv);
        o.w = f2bf(v[t].w * inv);
        dst[lane + 64 * t] = o;
    }
}

// ---------------------------------------------------------------------------
// Kernel 2: flash-style sim GEMM (NT, A=B=fn) + fixed-max exp accumulation.
// BK=32, 16 KiB LDS, UNIT-MAJOR staging permutation: chunk = 16 rows x 32 k
// (1 KiB); staging lane l fetches (row=l&15, unit=l>>4) so physical offset of
// (row,unit) = (unit*16+row)*16B. Fragment read addr = chunk_base + lane*16B:
// every ds_read_b128 covers a contiguous 1 KiB -> conflict-free (verified
// round 4: SQ_LDS_BANK_CONFLICT = 0), with round-1's lean register profile.
// NO min-waves clause: __launch_bounds__(256,3) in round 4 forced spills
// (WRITE_SIZE 4 MB -> 143 MB). Natural allocation = 2 waves/SIMD, no spills.
__global__ __launch_bounds__(256) void simgemm_kernel(const unsigned short* __restrict__ fn,
                                                      float* __restrict__ row_sum) {
    __shared__ __align__(16) unsigned short As[128 * 32];   // 8 KiB
    __shared__ __align__(16) unsigned short Bs[128 * 32];   // 8 KiB
    const int tid = threadIdx.x;
    const int w = tid >> 6, lane = tid & 63;
    const int q = lane >> 4, c16 = lane & 15;
    const int r0 = blockIdx.y * 128;
    const int cg0 = blockIdx.x * 512;
    const int wr = (w >> 1) * 64;  // wave's row base within tile
    const int wc = (w & 1) * 64;   // wave's col base within tile
    const int wr4 = (w >> 1) * 4;  // wave's A chunk base (16-row chunks)
    const int wc4 = (w & 1) * 4;   // wave's B chunk base
    // staging: wave w stages chunks 2w, 2w+1 of A and B.
    const int srow = lane & 15;          // row within chunk
    const int sue = (lane >> 4) * 8;     // unit element offset
    const int loff = lane * 8;           // LDS fragment element offset in chunk

    const unsigned short* pa0 = fn + (size_t)(r0 + w * 32 + srow) * D_DIM + sue;
    const unsigned short* pa1 = pa0 + 16 * D_DIM;

    float rs[4][4];                      // per-(row-subtile, reg) partial exp-sums
#pragma unroll
    for (int i = 0; i < 4; ++i)
#pragma unroll
        for (int r = 0; r < 4; ++r) rs[i][r] = 0.f;

    for (int ct = 0; ct < 4; ++ct) {
        const int c0 = cg0 + ct * 128;
        const unsigned short* qa0 = pa0;
        const unsigned short* qa1 = pa1;
        const unsigned short* pb0 = fn + (size_t)(c0 + w * 32 + srow) * D_DIM + sue;
        const unsigned short* pb1 = pb0 + 16 * D_DIM;

        f32x4 acc[4][4];
#pragma unroll
        for (int i = 0; i < 4; ++i)
#pragma unroll
            for (int j = 0; j < 4; ++j) acc[i][j] = (f32x4){0.f, 0.f, 0.f, 0.f};

        for (int kt = 0; kt < 32; ++kt) {
            __syncthreads();  // previous k-step's reads done before overwrite
            async_ld16(qa0, (void*)&As[(w * 2 + 0) * 512]);
            async_ld16(qa1, (void*)&As[(w * 2 + 1) * 512]);
            async_ld16(pb0, (void*)&Bs[(w * 2 + 0) * 512]);
            async_ld16(pb1, (void*)&Bs[(w * 2 + 1) * 512]);
            qa0 += 32; qa1 += 32; pb0 += 32; pb1 += 32;
            __syncthreads();  // drains vmcnt(0): staging visible

            short8 af[4], bf[4];
#pragma unroll
            for (int i = 0; i < 4; ++i)
                af[i] = *(const short8*)&As[(wr4 + i) * 512 + loff];
#pragma unroll
            for (int j = 0; j < 4; ++j)
                bf[j] = *(const short8*)&Bs[(wc4 + j) * 512 + loff];
#pragma unroll
            for (int i = 0; i < 4; ++i)
#pragma unroll
                for (int j = 0; j < 4; ++j)
                    acc[i][j] = __builtin_amdgcn_mfma_f32_16x16x32_bf16(af[i], bf[j], acc[i][j], 0, 0, 0);
        }

        // epilogue: exp(sim - M), diag masked, accumulate per-row
#pragma unroll
        for (int i = 0; i < 4; ++i) {
            const int growb = r0 + wr + i * 16 + q * 4;
#pragma unroll
            for (int r = 0; r < 4; ++r) {
                float s = 0.f;
#pragma unroll
                for (int j = 0; j < 4; ++j) {
                    const int gcol = c0 + wc + j * 16 + c16;
                    float sim = acc[i][j][r] * INV_T;
                    float e = __expf(sim - INV_T);
                    if (growb + r == gcol) e = 0.f;  // diagonal mask
                    s += e;
                }
                rs[i][r] += s;
            }
        }
    }

    // reduce across the 16 col-lanes of each quad, one atomic per row
#pragma unroll
    for (int i = 0; i < 4; ++i)
#pragma unroll
        for (int r = 0; r < 4; ++r) {
            float s = rs[i][r];
            s += __shfl_xor(s, 1);
            s += __shfl_xor(s, 2);
            s += __shfl_xor(s, 4);
            s += __shfl_xor(s, 8);
            if (c16 == 0) atomicAdd(&row_sum[r0 + wr + i * 16 + q * 4 + r], s);
        }
}

// ---------------------------------------------------------------------------
// Kernel 3: loss = mean_i [ M + log(row_sum_i) - s_target_i ]
__global__ __launch_bounds__(256) void loss_kernel(const float* __restrict__ row_sum,
                                                   const float* __restrict__ s_target,
                                                   float* __restrict__ out) {
    float local = 0.f;
    for (int i = threadIdx.x; i < N_ROWS; i += 256)
        local += (INV_T + __logf(row_sum[i])) - s_target[i];
#pragma unroll
    for (int off = 32; off; off >>= 1) local += __shfl_xor(local, off);
    __shared__ float part[4];
    if ((threadIdx.x & 63) == 0) part[threadIdx.x >> 6] = local;
    __syncthreads();
    if (threadIdx.x == 0)
        out[0] = (part[0] + part[1] + part[2] + part[3]) * (1.0f / N_ROWS);
}

// ---------------------------------------------------------------------------
extern "C" void kernel_launch(void* const* d_in, const int* in_sizes, int n_in,
                              void* d_out, int out_size, void* d_ws, size_t ws_size,
                              hipStream_t stream) {
    const float* feat = (const float*)d_in[0];
    float* out = (float*)d_out;
    char* ws = (char*)d_ws;

    unsigned short* fn = (unsigned short*)ws;                 // 8192*1024 bf16 = 16 MiB
    size_t off = (size_t)N_ROWS * D_DIM * sizeof(unsigned short);
    float* row_sum = (float*)(ws + off);  off += N_ROWS * sizeof(float);
    float* s_target = (float*)(ws + off);

    norm_kernel<<<N_ROWS / 4, 256, 0, stream>>>(feat, fn, row_sum, s_target);
    simgemm_kernel<<<dim3(16, 64), 256, 0, stream>>>(fn, row_sum);
    loss_kernel<<<1, 256, 0, stream>>>(row_sum, s_target, out);
}

// Round 6
// 270.434 us; speedup vs baseline: 1.5598x; 1.2582x over previous
//
#include <hip/hip_runtime.h>
#include <hip/hip_bf16.h>

// Problem constants
#define N_ROWS 8192
#define D_DIM  1024
#define HALF_N 4096
constexpr float INV_T = 1.0f / 0.07f;   // 14.2857143 — also the fixed softmax max M

typedef __attribute__((ext_vector_type(8))) short short8;  // 8 bf16 (4 VGPRs)
typedef __attribute__((ext_vector_type(4))) float f32x4;

__device__ __forceinline__ unsigned short f2bf(float x) {
    __hip_bfloat16 h = __float2bfloat16(x);
    return *reinterpret_cast<unsigned short*>(&h);
}

// async global->LDS, 16B/lane. LDS dest is wave-uniform base + lane*16.
__device__ __forceinline__ void async_ld16(const void* g, void* lds) {
    __builtin_amdgcn_global_load_lds(
        (const __attribute__((address_space(1))) void*)g,
        (__attribute__((address_space(3))) void*)lds,
        16, 0, 0);
}

// ---------------------------------------------------------------------------
// Kernel 1: row norms + bf16 normalized copy + fp32-exact target similarity
// + row_sum zeroing. One wave per row; pair row (i+4096 mod 8192) is read
// again here (L3-resident) to avoid a separate target kernel.
__global__ __launch_bounds__(256) void norm_kernel(const float* __restrict__ feat,
                                                   unsigned short* __restrict__ fn,
                                                   float* __restrict__ row_sum,
                                                   float* __restrict__ s_target) {
    const int w = threadIdx.x >> 6, lane = threadIdx.x & 63;
    const int row = blockIdx.x * 4 + w;
    const int pair = (row + HALF_N) & (N_ROWS - 1);
    const float4* src = (const float4*)(feat + (size_t)row * D_DIM);
    const float4* psrc = (const float4*)(feat + (size_t)pair * D_DIM);
    float4 v[4];
    float ss = 0.f, sp = 0.f, dp = 0.f;
#pragma unroll
    for (int t = 0; t < 4; ++t) {
        v[t] = src[lane + 64 * t];
        float4 p = psrc[lane + 64 * t];
        ss += v[t].x * v[t].x + v[t].y * v[t].y + v[t].z * v[t].z + v[t].w * v[t].w;
        sp += p.x * p.x + p.y * p.y + p.z * p.z + p.w * p.w;
        dp += v[t].x * p.x + v[t].y * p.y + v[t].z * p.z + v[t].w * p.w;
    }
#pragma unroll
    for (int off = 32; off; off >>= 1) {
        ss += __shfl_xor(ss, off);
        sp += __shfl_xor(sp, off);
        dp += __shfl_xor(dp, off);
    }
    float nrm = fmaxf(sqrtf(ss), 1e-8f);
    if (lane == 0) {
        row_sum[row] = 0.f;
        s_target[row] = dp / (nrm * fmaxf(sqrtf(sp), 1e-8f)) * INV_T;
    }
    const float inv = 1.0f / nrm;
    ushort4* dst = (ushort4*)(fn + (size_t)row * D_DIM);
#pragma unroll
    for (int t = 0; t < 4; ++t) {
        ushort4 o;
        o.x = f2bf(v[t].x * inv);
        o.y = f2bf(v[t].y * inv);
        o.z = f2bf(v[t].z * inv);
        o.w = f2bf(v[t].w * inv);
        dst[lane + 64 * t] = o;
    }
}

// ---------------------------------------------------------------------------
// Kernel 2: flash-style sim GEMM (NT, A=B=fn) + fixed-max exp accumulation.
// BK=32, 16 KiB LDS. Staging uses ROTATE-WITHIN-ROW swizzle: lane l fetches
// row l>>2, logical unit (l&3) ^ f(row), f(r)=(r>>1)&3. Properties:
//  * global: each lane-quad reads one contiguous 64 B run of one row
//    (identical segment-per-quad locality to round 1 — round 5's unit-major
//    map scattered quads across 4 lines and cost +39 us);
//  * LDS: logical unit u of row r lands at r*64 + (u^f(r))*16 B; fragment
//    read addr c16*64 + (q^f(c16))*16 puts exactly 2 of 16 lanes on each
//    4-bank group -> conflict-free b128 (round 2/3 result, but now the XOR
//    is a kt/ct-invariant PROLOGUE computation: 1 base reg + const ds
//    offsets, so no register blowup — rounds 2/3 died at 200-220 VGPR).
// No min-waves clause (round 4: forcing 3 waves/SIMD spilled, WRITE 143 MB).
__global__ __launch_bounds__(256) void simgemm_kernel(const unsigned short* __restrict__ fn,
                                                      float* __restrict__ row_sum) {
    __shared__ __align__(16) unsigned short As[128 * 32];   // 8 KiB
    __shared__ __align__(16) unsigned short Bs[128 * 32];   // 8 KiB
    const int tid = threadIdx.x;
    const int w = tid >> 6, lane = tid & 63;
    const int q = lane >> 4, c16 = lane & 15;
    const int r0 = blockIdx.y * 128;
    const int cg0 = blockIdx.x * 512;
    const int wr = (w >> 1) * 64;  // wave's row base within tile
    const int wc = (w & 1) * 64;   // wave's col base within tile
    const int wr4 = (w >> 1) * 4;  // wave's A chunk base (16-row chunks)
    const int wc4 = (w & 1) * 4;   // wave's B chunk base
    // staging: wave w stages chunks 2w, 2w+1 (rows w*32 .. w*32+31).
    const int srow = lane >> 2;                              // row within chunk
    const int skoff = ((lane & 3) ^ ((lane >> 3) & 3)) * 8;  // swizzled unit elem offset
    // fragment read element offset within a chunk (kt/ct-invariant):
    const int loff = c16 * 32 + (q ^ ((c16 >> 1) & 3)) * 8;

    const unsigned short* pa0 = fn + (size_t)(r0 + w * 32 + srow) * D_DIM + skoff;
    const unsigned short* pa1 = pa0 + 16 * D_DIM;

    float rs[4][4];                      // per-(row-subtile, reg) partial exp-sums
#pragma unroll
    for (int i = 0; i < 4; ++i)
#pragma unroll
        for (int r = 0; r < 4; ++r) rs[i][r] = 0.f;

    for (int ct = 0; ct < 4; ++ct) {
        const int c0 = cg0 + ct * 128;
        const unsigned short* qa0 = pa0;
        const unsigned short* qa1 = pa1;
        const unsigned short* pb0 = fn + (size_t)(c0 + w * 32 + srow) * D_DIM + skoff;
        const unsigned short* pb1 = pb0 + 16 * D_DIM;

        f32x4 acc[4][4];
#pragma unroll
        for (int i = 0; i < 4; ++i)
#pragma unroll
            for (int j = 0; j < 4; ++j) acc[i][j] = (f32x4){0.f, 0.f, 0.f, 0.f};

        for (int kt = 0; kt < 32; ++kt) {
            __syncthreads();  // previous k-step's reads done before overwrite
            async_ld16(qa0, (void*)&As[(w * 2 + 0) * 512]);
            async_ld16(qa1, (void*)&As[(w * 2 + 1) * 512]);
            async_ld16(pb0, (void*)&Bs[(w * 2 + 0) * 512]);
            async_ld16(pb1, (void*)&Bs[(w * 2 + 1) * 512]);
            qa0 += 32; qa1 += 32; pb0 += 32; pb1 += 32;
            __syncthreads();  // drains vmcnt(0): staging visible

            short8 af[4], bf[4];
#pragma unroll
            for (int i = 0; i < 4; ++i)
                af[i] = *(const short8*)&As[(wr4 + i) * 512 + loff];
#pragma unroll
            for (int j = 0; j < 4; ++j)
                bf[j] = *(const short8*)&Bs[(wc4 + j) * 512 + loff];
#pragma unroll
            for (int i = 0; i < 4; ++i)
#pragma unroll
                for (int j = 0; j < 4; ++j)
                    acc[i][j] = __builtin_amdgcn_mfma_f32_16x16x32_bf16(af[i], bf[j], acc[i][j], 0, 0, 0);
        }

        // epilogue: exp(sim - M), diag masked, accumulate per-row
#pragma unroll
        for (int i = 0; i < 4; ++i) {
            const int growb = r0 + wr + i * 16 + q * 4;
#pragma unroll
            for (int r = 0; r < 4; ++r) {
                float s = 0.f;
#pragma unroll
                for (int j = 0; j < 4; ++j) {
                    const int gcol = c0 + wc + j * 16 + c16;
                    float sim = acc[i][j][r] * INV_T;
                    float e = __expf(sim - INV_T);
                    if (growb + r == gcol) e = 0.f;  // diagonal mask
                    s += e;
                }
                rs[i][r] += s;
            }
        }
    }

    // reduce across the 16 col-lanes of each quad, one atomic per row
#pragma unroll
    for (int i = 0; i < 4; ++i)
#pragma unroll
        for (int r = 0; r < 4; ++r) {
            float s = rs[i][r];
            s += __shfl_xor(s, 1);
            s += __shfl_xor(s, 2);
            s += __shfl_xor(s, 4);
            s += __shfl_xor(s, 8);
            if (c16 == 0) atomicAdd(&row_sum[r0 + wr + i * 16 + q * 4 + r], s);
        }
}

// ---------------------------------------------------------------------------
// Kernel 3: loss = mean_i [ M + log(row_sum_i) - s_target_i ]
__global__ __launch_bounds__(256) void loss_kernel(const float* __restrict__ row_sum,
                                                   const float* __restrict__ s_target,
                                                   float* __restrict__ out) {
    float local = 0.f;
    for (int i = threadIdx.x; i < N_ROWS; i += 256)
        local += (INV_T + __logf(row_sum[i])) - s_target[i];
#pragma unroll
    for (int off = 32; off; off >>= 1) local += __shfl_xor(local, off);
    __shared__ float part[4];
    if ((threadIdx.x & 63) == 0) part[threadIdx.x >> 6] = local;
    __syncthreads();
    if (threadIdx.x == 0)
        out[0] = (part[0] + part[1] + part[2] + part[3]) * (1.0f / N_ROWS);
}

// ---------------------------------------------------------------------------
extern "C" void kernel_launch(void* const* d_in, const int* in_sizes, int n_in,
                              void* d_out, int out_size, void* d_ws, size_t ws_size,
                              hipStream_t stream) {
    const float* feat = (const float*)d_in[0];
    float* out = (float*)d_out;
    char* ws = (char*)d_ws;

    unsigned short* fn = (unsigned short*)ws;                 // 8192*1024 bf16 = 16 MiB
    size_t off = (size_t)N_ROWS * D_DIM * sizeof(unsigned short);
    float* row_sum = (float*)(ws + off);  off += N_ROWS * sizeof(float);
    float* s_target = (float*)(ws + off);

    norm_kernel<<<N_ROWS / 4, 256, 0, stream>>>(feat, fn, row_sum, s_target);
    simgemm_kernel<<<dim3(16, 64), 256, 0, stream>>>(fn, row_sum);
    loss_kernel<<<1, 256, 0, stream>>>(row_sum, s_target, out);
}